// Round 2
// baseline (2270.714 us; speedup 1.0000x reference)
//
#include <hip/hip_runtime.h>

typedef unsigned short bf16_t;  // raw bf16 bits

static constexpr int NU = 100000;   // users
static constexpr int NG = 20000;    // games
static constexpr int HD = 256;      // hidden
static constexpr int EE = 1000000;  // edges per direction
static constexpr int SS = 500000;   // score pairs

// ---------------- bf16 helpers ----------------
__device__ __forceinline__ float b2f(bf16_t u) {
    union { unsigned int i; float f; } x; x.i = ((unsigned int)u) << 16; return x.f;
}
__device__ __forceinline__ bf16_t f2b(float f) {
    union { float f; unsigned int i; } x; x.f = f;
    unsigned int r = x.i + 0x7FFF + ((x.i >> 16) & 1);  // RNE
    return (bf16_t)(r >> 16);
}
__device__ __forceinline__ float4 load4f(const float* p) { return *(const float4*)p; }
__device__ __forceinline__ float4 load4f(const bf16_t* p) {
    ushort4 u = *(const ushort4*)p;
    return make_float4(b2f(u.x), b2f(u.y), b2f(u.z), b2f(u.w));
}
__device__ __forceinline__ float2 load2f(const float* p) { return *(const float2*)p; }
__device__ __forceinline__ float2 load2f(const bf16_t* p) {
    ushort2 u = *(const ushort2*)p;
    return make_float2(b2f(u.x), b2f(u.y));
}
__device__ __forceinline__ void store4(float* p, float4 v) { *(float4*)p = v; }
__device__ __forceinline__ void store4(bf16_t* p, float4 v) {
    ushort4 u = make_ushort4(f2b(v.x), f2b(v.y), f2b(v.z), f2b(v.w));
    *(ushort4*)p = u;
}
__device__ __forceinline__ void store2(float* p, float2 v) { *(float2*)p = v; }
__device__ __forceinline__ void store2(bf16_t* p, float2 v) {
    ushort2 u = make_ushort2(f2b(v.x), f2b(v.y));
    *(ushort2*)p = u;
}

// ---------------- misc small kernels ----------------
__global__ void zero_i32(int* __restrict__ p, int n) {
    for (int i = blockIdx.x * 256 + threadIdx.x; i < n; i += gridDim.x * 256) p[i] = 0;
}

__global__ void build_xg(const float* __restrict__ xgame,
                         const float* __restrict__ emb,
                         float* __restrict__ xg) {
    int id = blockIdx.x * 256 + threadIdx.x;
    if (id >= NG * 128) return;
    int r = id >> 7, c = id & 127;
    xg[id] = (c < 64) ? xgame[(r << 6) + c] : emb[(r << 6) + (c - 64)];
}

// ---------------- CSR build ----------------
__global__ void histo(const int* __restrict__ dst, int* __restrict__ cnt, int E) {
    for (int i = blockIdx.x * blockDim.x + threadIdx.x; i < E; i += gridDim.x * blockDim.x)
        atomicAdd(&cnt[dst[i]], 1);
}

__global__ void scan1(const int* __restrict__ cnt, int* __restrict__ rowptr,
                      int* __restrict__ bsum, int n) {
    __shared__ int sd[256];
    int t = threadIdx.x;
    int base = blockIdx.x * 1024;
    int v[4]; int s = 0;
#pragma unroll
    for (int i = 0; i < 4; i++) {
        int idx = base + t * 4 + i;
        v[i] = (idx < n) ? cnt[idx] : 0;
        s += v[i];
    }
    sd[t] = s;
    __syncthreads();
    for (int off = 1; off < 256; off <<= 1) {
        int y = (t >= off) ? sd[t - off] : 0;
        __syncthreads();
        sd[t] += y;
        __syncthreads();
    }
    int run = sd[t] - s;
#pragma unroll
    for (int i = 0; i < 4; i++) {
        int idx = base + t * 4 + i;
        if (idx < n) rowptr[idx] = run;
        run += v[i];
    }
    if (t == 255) bsum[blockIdx.x] = sd[255];
}

__global__ void scan2(int* bsum, int nb) {
    if (threadIdx.x == 0 && blockIdx.x == 0) {
        int run = 0;
        for (int i = 0; i < nb; i++) { int v = bsum[i]; bsum[i] = run; run += v; }
    }
}

__global__ void scan3(int* __restrict__ rowptr, const int* __restrict__ bsum, int n, int E) {
    int t = threadIdx.x;
    int base = blockIdx.x * 1024;
    int add = bsum[blockIdx.x];
#pragma unroll
    for (int i = 0; i < 4; i++) {
        int idx = base + t * 4 + i;
        if (idx < n) rowptr[idx] += add;
    }
    if (blockIdx.x == 0 && t == 0) rowptr[n] = E;
}

__global__ void scatter_edges(const int* __restrict__ src, const int* __restrict__ dst,
                              const float* __restrict__ ew, const int* __restrict__ rowptr,
                              int* __restrict__ cursor, int2* __restrict__ edges, int E) {
    for (int i = blockIdx.x * blockDim.x + threadIdx.x; i < E; i += gridDim.x * blockDim.x) {
        int d = dst[i];
        int p = rowptr[d] + atomicAdd(&cursor[d], 1);
        edges[p] = make_int2(src[i], __float_as_int(ew[i]));
    }
}

// ---------------- segment sum (CSR, one wave per destination row) ----------------
template <typename SrcT, typename OutT, int D>
__global__ __launch_bounds__(256) void seg_sum(
    const SrcT* __restrict__ feat, const int* __restrict__ rowptr,
    const int2* __restrict__ edges, OutT* __restrict__ out, int n_rows) {
    int wid = (blockIdx.x * 256 + threadIdx.x) >> 6;
    int lane = threadIdx.x & 63;
    if (wid >= n_rows) return;
    int beg = rowptr[wid], end = rowptr[wid + 1];
    if (D == 256) {
        float4 acc = make_float4(0.f, 0.f, 0.f, 0.f);
        const SrcT* base = feat + lane * 4;
        for (int e = beg; e < end; ++e) {
            int2 ed = edges[e];
            float w = __int_as_float(ed.y);
            float4 v = load4f(base + (size_t)ed.x * 256);
            acc.x = fmaf(w, v.x, acc.x);
            acc.y = fmaf(w, v.y, acc.y);
            acc.z = fmaf(w, v.z, acc.z);
            acc.w = fmaf(w, v.w, acc.w);
        }
        store4(&out[(size_t)wid * 256 + lane * 4], acc);
    } else {  // D == 128
        float2 acc = make_float2(0.f, 0.f);
        const SrcT* base = feat + lane * 2;
        for (int e = beg; e < end; ++e) {
            int2 ed = edges[e];
            float w = __int_as_float(ed.y);
            float2 v = load2f(base + (size_t)ed.x * 128);
            acc.x = fmaf(w, v.x, acc.x);
            acc.y = fmaf(w, v.y, acc.y);
        }
        store2(&out[(size_t)wid * 128 + lane * 2], acc);
    }
}

// ---------------- GEMM: C(bf16) = [A1@W1 (+ A2@W2)] (+bias) (+C) (relu?) ----------------
template <typename TA>
__device__ __forceinline__ void gemm_pass(const TA* __restrict__ A, const float* __restrict__ W,
                                          float (&acc)[8][8], float (&As)[16][132],
                                          float (&Bs)[16][132], int M, int K,
                                          int rowBase, int colBase, int t) {
    const int tx = t & 15, ty = t >> 4;
    for (int k0 = 0; k0 < K; k0 += 16) {
#pragma unroll
        for (int i = 0; i < 2; i++) {
            int li = t + i * 256;           // 0..511
            int m = li >> 2, kq = li & 3;   // row in tile, float4 within k-strip
            int gm = rowBase + m;
            float4 v = make_float4(0.f, 0.f, 0.f, 0.f);
            if (gm < M) v = load4f(&A[(size_t)gm * K + k0 + kq * 4]);
            As[kq * 4 + 0][m] = v.x;
            As[kq * 4 + 1][m] = v.y;
            As[kq * 4 + 2][m] = v.z;
            As[kq * 4 + 3][m] = v.w;
        }
#pragma unroll
        for (int i = 0; i < 2; i++) {
            int li = t + i * 256;
            int k = li >> 5, cq = li & 31;
            float4 v = *(const float4*)&W[(size_t)(k0 + k) * HD + colBase + cq * 4];
            *(float4*)&Bs[k][cq * 4] = v;
        }
        __syncthreads();
#pragma unroll
        for (int k = 0; k < 16; k++) {
            float4 a0 = *(const float4*)&As[k][ty * 4];
            float4 a1 = *(const float4*)&As[k][64 + ty * 4];
            float4 b0 = *(const float4*)&Bs[k][tx * 4];
            float4 b1 = *(const float4*)&Bs[k][64 + tx * 4];
            float a[8] = {a0.x, a0.y, a0.z, a0.w, a1.x, a1.y, a1.z, a1.w};
            float b[8] = {b0.x, b0.y, b0.z, b0.w, b1.x, b1.y, b1.z, b1.w};
#pragma unroll
            for (int i = 0; i < 8; i++)
#pragma unroll
                for (int j = 0; j < 8; j++) acc[i][j] = fmaf(a[i], b[j], acc[i][j]);
        }
        __syncthreads();
    }
}

template <typename TA1, typename TA2, bool TWOPASS>
__global__ __launch_bounds__(256) void gemm_fused(
    const TA1* __restrict__ A1, const float* __restrict__ W1,
    const TA2* __restrict__ A2, const float* __restrict__ W2,
    const float* __restrict__ bias, bf16_t* __restrict__ C,
    int M, int K, int addc, int relu) {
    __shared__ float As[16][132];
    __shared__ float Bs[16][132];
    const int t = threadIdx.x;
    const int tx = t & 15, ty = t >> 4;
    const int rowBase = blockIdx.x * 128;
    const int colBase = blockIdx.y * 128;
    float acc[8][8];
#pragma unroll
    for (int i = 0; i < 8; i++)
#pragma unroll
        for (int j = 0; j < 8; j++) acc[i][j] = 0.f;

    gemm_pass<TA1>(A1, W1, acc, As, Bs, M, K, rowBase, colBase, t);
    if (TWOPASS) gemm_pass<TA2>(A2, W2, acc, As, Bs, M, K, rowBase, colBase, t);

#pragma unroll
    for (int ig = 0; ig < 2; ++ig) {
#pragma unroll
        for (int ii = 0; ii < 4; ++ii) {
            int row = rowBase + ig * 64 + ty * 4 + ii;
            if (row >= M) continue;
#pragma unroll
            for (int jg = 0; jg < 2; ++jg) {
                int col = colBase + jg * 64 + tx * 4;
                float4 v;
                v.x = acc[ig * 4 + ii][jg * 4 + 0];
                v.y = acc[ig * 4 + ii][jg * 4 + 1];
                v.z = acc[ig * 4 + ii][jg * 4 + 2];
                v.w = acc[ig * 4 + ii][jg * 4 + 3];
                if (bias) {
                    float4 b = *(const float4*)&bias[col];
                    v.x += b.x; v.y += b.y; v.z += b.z; v.w += b.w;
                }
                bf16_t* cp = &C[(size_t)row * HD + col];
                if (addc) {
                    float4 e = load4f((const bf16_t*)cp);
                    v.x += e.x; v.y += e.y; v.z += e.z; v.w += e.w;
                }
                if (relu) {
                    v.x = fmaxf(v.x, 0.f); v.y = fmaxf(v.y, 0.f);
                    v.z = fmaxf(v.z, 0.f); v.w = fmaxf(v.w, 0.f);
                }
                store4(cp, v);
            }
        }
    }
}

// ---------------- decoder ----------------
__global__ __launch_bounds__(256) void decode(
    const bf16_t* __restrict__ u3, const bf16_t* __restrict__ g3,
    const int* __restrict__ row, const int* __restrict__ col,
    float* __restrict__ out, int S) {
    int wid = (blockIdx.x * 256 + threadIdx.x) >> 6;
    int lane = threadIdx.x & 63;
    if (wid >= S) return;
    int r = row[wid], c = col[wid];
    float4 a = load4f(&u3[(size_t)r * 256 + lane * 4]);
    float4 b = load4f(&g3[(size_t)c * 256 + lane * 4]);
    float s = a.x * b.x + a.y * b.y + a.z * b.z + a.w * b.w;
#pragma unroll
    for (int d = 32; d > 0; d >>= 1) s += __shfl_down(s, d, 64);
    if (lane == 0) out[wid] = s;
}

extern "C" void kernel_launch(void* const* d_in, const int* in_sizes, int n_in,
                              void* d_out, int out_size, void* d_ws, size_t ws_size,
                              hipStream_t stream) {
    const float* x_user  = (const float*)d_in[0];
    const float* x_game  = (const float*)d_in[1];
    const float* emb_game= (const float*)d_in[2];
    const float* ew_ug   = (const float*)d_in[3];
    const float* ew_gu   = (const float*)d_in[4];
    const int* src_ug    = (const int*)d_in[5];
    const int* dst_ug    = (const int*)d_in[6];
    const int* src_gu    = (const int*)d_in[7];
    const int* dst_gu    = (const int*)d_in[8];
    const int* score_row = (const int*)d_in[9];
    const int* score_col = (const int*)d_in[10];
    const float* Wr_ug[3] = {(const float*)d_in[11], (const float*)d_in[17], (const float*)d_in[23]};
    const float* b_ug[3]  = {(const float*)d_in[12], (const float*)d_in[18], (const float*)d_in[24]};
    const float* Wo_g[3]  = {(const float*)d_in[13], (const float*)d_in[19], (const float*)d_in[25]};
    const float* Wr_gu[3] = {(const float*)d_in[14], (const float*)d_in[20], (const float*)d_in[26]};
    const float* b_gu[3]  = {(const float*)d_in[15], (const float*)d_in[21], (const float*)d_in[27]};
    const float* Wo_u[3]  = {(const float*)d_in[16], (const float*)d_in[22], (const float*)d_in[28]};
    float* out = (float*)d_out;
    (void)in_sizes; (void)n_in; (void)out_size;

    // workspace layout (~181 MB); bail cleanly if d_ws is too small (no OOB fault)
    constexpr size_t WS_NEEDED = 185u * 1000u * 1000u;
    if (ws_size < WS_NEEDED) return;

    char* ws = (char*)d_ws;
    size_t off = 0;
    auto alloc = [&](size_t bytes) -> void* {
        void* p = ws + off;
        off += (bytes + 255) & ~(size_t)255;
        return p;
    };
    float*  xg   = (float*) alloc((size_t)NG * 128 * 4);  // 10.24 MB
    bf16_t* uA   = (bf16_t*)alloc((size_t)NU * HD * 2);   // 51.2 MB
    bf16_t* uB   = (bf16_t*)alloc((size_t)NU * HD * 2);   // 51.2 MB
    bf16_t* gA   = (bf16_t*)alloc((size_t)NG * HD * 2);   // 10.24 MB
    bf16_t* gB   = (bf16_t*)alloc((size_t)NG * HD * 2);   // 10.24 MB
    bf16_t* Yg   = (bf16_t*)alloc((size_t)NG * HD * 2);   // 10.24 MB
    float*  Mbuf = (float*) alloc((size_t)NG * HD * 4);   // 20.48 MB
    int2*   e_ug = (int2*)  alloc((size_t)EE * 8);        // 8 MB
    int2*   e_gu = (int2*)  alloc((size_t)EE * 8);        // 8 MB
    int* rowptr_g = (int*)alloc((NG + 1) * 4);
    int* rowptr_u = (int*)alloc((NU + 1) * 4);
    int* cnt_g    = (int*)alloc(NG * 4);
    int* cnt_u    = (int*)alloc(NU * 4);
    int* bsum     = (int*)alloc(1024 * 4);

    auto build_csr = [&](const int* dst, const int* src, const float* ew, int n,
                         int* rowptr, int* cnt, int2* edges) {
        zero_i32<<<256, 256, 0, stream>>>(cnt, n);
        histo<<<1024, 256, 0, stream>>>(dst, cnt, EE);
        int nb = (n + 1023) / 1024;
        scan1<<<nb, 256, 0, stream>>>(cnt, rowptr, bsum, n);
        scan2<<<1, 64, 0, stream>>>(bsum, nb);
        scan3<<<nb, 256, 0, stream>>>(rowptr, bsum, n, EE);
        zero_i32<<<256, 256, 0, stream>>>(cnt, n);
        scatter_edges<<<1024, 256, 0, stream>>>(src, dst, ew, rowptr, cnt, edges, EE);
    };

    build_xg<<<(NG * 128 + 255) / 256, 256, 0, stream>>>(x_game, emb_game, xg);
    build_csr(dst_ug, src_ug, ew_ug, NG, rowptr_g, cnt_g, e_ug);
    build_csr(dst_gu, src_gu, ew_gu, NU, rowptr_u, cnt_u, e_gu);

    const dim3 GG((NG + 127) / 128, 2), GU((NU + 127) / 128, 2);
    const int SEG_G = (NG + 3) / 4, SEG_U = (NU + 3) / 4;

    // ---- Layer 1 (K=128) ----
    seg_sum<float, float, 128><<<SEG_G, 256, 0, stream>>>(x_user, rowptr_g, e_ug, Mbuf, NG);
    gemm_fused<float, float, true><<<GG, 256, 0, stream>>>(
        Mbuf, Wr_ug[0], xg, Wo_g[0], b_ug[0], gA, NG, 128, 0, 1);
    gemm_fused<float, float, false><<<GG, 256, 0, stream>>>(
        xg, Wr_gu[0], (const float*)nullptr, nullptr, nullptr, Yg, NG, 128, 0, 0);
    seg_sum<bf16_t, bf16_t, 256><<<SEG_U, 256, 0, stream>>>(Yg, rowptr_u, e_gu, uA, NU);
    gemm_fused<float, float, false><<<GU, 256, 0, stream>>>(
        x_user, Wo_u[0], (const float*)nullptr, nullptr, b_gu[0], uA, NU, 128, 1, 1);

    // ---- Layer 2 (K=256) ----
    seg_sum<bf16_t, float, 256><<<SEG_G, 256, 0, stream>>>(uA, rowptr_g, e_ug, Mbuf, NG);
    gemm_fused<float, bf16_t, true><<<GG, 256, 0, stream>>>(
        Mbuf, Wr_ug[1], gA, Wo_g[1], b_ug[1], gB, NG, 256, 0, 1);
    gemm_fused<bf16_t, float, false><<<GG, 256, 0, stream>>>(
        gA, Wr_gu[1], (const float*)nullptr, nullptr, nullptr, Yg, NG, 256, 0, 0);
    seg_sum<bf16_t, bf16_t, 256><<<SEG_U, 256, 0, stream>>>(Yg, rowptr_u, e_gu, uB, NU);
    gemm_fused<bf16_t, float, false><<<GU, 256, 0, stream>>>(
        uA, Wo_u[1], (const float*)nullptr, nullptr, b_gu[1], uB, NU, 256, 1, 1);

    // ---- Layer 3 (K=256, no relu) ----
    seg_sum<bf16_t, float, 256><<<SEG_G, 256, 0, stream>>>(uB, rowptr_g, e_ug, Mbuf, NG);
    gemm_fused<float, bf16_t, true><<<GG, 256, 0, stream>>>(
        Mbuf, Wr_ug[2], gB, Wo_g[2], b_ug[2], gA, NG, 256, 0, 0);
    gemm_fused<bf16_t, float, false><<<GG, 256, 0, stream>>>(
        gB, Wr_gu[2], (const float*)nullptr, nullptr, nullptr, Yg, NG, 256, 0, 0);
    seg_sum<bf16_t, bf16_t, 256><<<SEG_U, 256, 0, stream>>>(Yg, rowptr_u, e_gu, uA, NU);
    gemm_fused<bf16_t, float, false><<<GU, 256, 0, stream>>>(
        uB, Wo_u[2], (const float*)nullptr, nullptr, b_gu[2], uA, NU, 256, 1, 0);

    // ---- decode ----
    decode<<<(SS + 3) / 4, 256, 0, stream>>>(uA, gA, score_row, score_col, out, SS);
}

// Round 3
// 1548.168 us; speedup vs baseline: 1.4667x; 1.4667x over previous
//
#include <hip/hip_runtime.h>

typedef unsigned short bf16_t;  // raw bf16 bits
typedef __attribute__((ext_vector_type(8))) short bf16x8;
typedef __attribute__((ext_vector_type(4))) float f32x4;

static constexpr int NU = 100000;   // users
static constexpr int NG = 20000;    // games
static constexpr int HD = 256;      // hidden
static constexpr int EE = 1000000;  // edges per direction
static constexpr int SS = 500000;   // score pairs

// ---------------- bf16 helpers ----------------
__device__ __forceinline__ float b2f(bf16_t u) {
    union { unsigned int i; float f; } x; x.i = ((unsigned int)u) << 16; return x.f;
}
__device__ __forceinline__ bf16_t f2b(float f) {
    union { float f; unsigned int i; } x; x.f = f;
    unsigned int r = x.i + 0x7FFF + ((x.i >> 16) & 1);  // RNE
    return (bf16_t)(r >> 16);
}
__device__ __forceinline__ float4 load4f(const bf16_t* p) {
    ushort4 u = *(const ushort4*)p;
    return make_float4(b2f(u.x), b2f(u.y), b2f(u.z), b2f(u.w));
}
__device__ __forceinline__ float2 load2f(const bf16_t* p) {
    ushort2 u = *(const ushort2*)p;
    return make_float2(b2f(u.x), b2f(u.y));
}
__device__ __forceinline__ void store4(bf16_t* p, float4 v) {
    *(ushort4*)p = make_ushort4(f2b(v.x), f2b(v.y), f2b(v.z), f2b(v.w));
}
__device__ __forceinline__ void store2(bf16_t* p, float2 v) {
    *(ushort2*)p = make_ushort2(f2b(v.x), f2b(v.y));
}

// ---------------- misc small kernels ----------------
__global__ void zero_i32(int* __restrict__ p, int n) {
    for (int i = blockIdx.x * 256 + threadIdx.x; i < n; i += gridDim.x * 256) p[i] = 0;
}

__global__ void cvt_f2b(const float* __restrict__ in, bf16_t* __restrict__ out, int n4) {
    int i = blockIdx.x * 256 + threadIdx.x;
    if (i >= n4) return;
    float4 v = ((const float4*)in)[i];
    ((ushort4*)out)[i] = make_ushort4(f2b(v.x), f2b(v.y), f2b(v.z), f2b(v.w));
}

__global__ void build_xg(const float* __restrict__ xgame,
                         const float* __restrict__ emb,
                         bf16_t* __restrict__ xg) {
    int id = blockIdx.x * 256 + threadIdx.x;
    if (id >= NG * 128) return;
    int r = id >> 7, c = id & 127;
    float v = (c < 64) ? xgame[(r << 6) + c] : emb[(r << 6) + (c - 64)];
    xg[id] = f2b(v);
}

// W: K x 256 fp32 row-major -> Wt: 256 x K bf16 row-major (transpose+convert)
__global__ void wt_bf16(const float* __restrict__ W, bf16_t* __restrict__ Wt, int K) {
    int id = blockIdx.x * 256 + threadIdx.x;
    if (id >= K * HD) return;
    int k = id >> 8, n = id & 255;
    Wt[(size_t)n * K + k] = f2b(W[id]);
}

// ---------------- CSR build ----------------
__global__ void histo(const int* __restrict__ dst, int* __restrict__ cnt, int E) {
    for (int i = blockIdx.x * blockDim.x + threadIdx.x; i < E; i += gridDim.x * blockDim.x)
        atomicAdd(&cnt[dst[i]], 1);
}

__global__ void scan1(const int* __restrict__ cnt, int* __restrict__ rowptr,
                      int* __restrict__ bsum, int n) {
    __shared__ int sd[256];
    int t = threadIdx.x;
    int base = blockIdx.x * 1024;
    int v[4]; int s = 0;
#pragma unroll
    for (int i = 0; i < 4; i++) {
        int idx = base + t * 4 + i;
        v[i] = (idx < n) ? cnt[idx] : 0;
        s += v[i];
    }
    sd[t] = s;
    __syncthreads();
    for (int off = 1; off < 256; off <<= 1) {
        int y = (t >= off) ? sd[t - off] : 0;
        __syncthreads();
        sd[t] += y;
        __syncthreads();
    }
    int run = sd[t] - s;
#pragma unroll
    for (int i = 0; i < 4; i++) {
        int idx = base + t * 4 + i;
        if (idx < n) rowptr[idx] = run;
        run += v[i];
    }
    if (t == 255) bsum[blockIdx.x] = sd[255];
}

__global__ void scan2(int* bsum, int nb) {
    if (threadIdx.x == 0 && blockIdx.x == 0) {
        int run = 0;
        for (int i = 0; i < nb; i++) { int v = bsum[i]; bsum[i] = run; run += v; }
    }
}

__global__ void scan3(int* __restrict__ rowptr, const int* __restrict__ bsum, int n, int E) {
    int t = threadIdx.x;
    int base = blockIdx.x * 1024;
    int add = bsum[blockIdx.x];
#pragma unroll
    for (int i = 0; i < 4; i++) {
        int idx = base + t * 4 + i;
        if (idx < n) rowptr[idx] += add;
    }
    if (blockIdx.x == 0 && t == 0) rowptr[n] = E;
}

__global__ void scatter_edges(const int* __restrict__ src, const int* __restrict__ dst,
                              const float* __restrict__ ew, const int* __restrict__ rowptr,
                              int* __restrict__ cursor, int2* __restrict__ edges, int E) {
    for (int i = blockIdx.x * blockDim.x + threadIdx.x; i < E; i += gridDim.x * blockDim.x) {
        int d = dst[i];
        int p = rowptr[d] + atomicAdd(&cursor[d], 1);
        edges[p] = make_int2(src[i], __float_as_int(ew[i]));
    }
}

// ---------------- segment sum (CSR, one wave per destination row), bf16 ----------------
template <int D>
__global__ __launch_bounds__(256) void seg_sum(
    const bf16_t* __restrict__ feat, const int* __restrict__ rowptr,
    const int2* __restrict__ edges, bf16_t* __restrict__ out, int n_rows) {
    int wid = (blockIdx.x * 256 + threadIdx.x) >> 6;
    int lane = threadIdx.x & 63;
    if (wid >= n_rows) return;
    int beg = rowptr[wid], end = rowptr[wid + 1];
    if (D == 256) {
        float4 acc = make_float4(0.f, 0.f, 0.f, 0.f);
        const bf16_t* base = feat + lane * 4;
        for (int e = beg; e < end; ++e) {
            int2 ed = edges[e];
            float w = __int_as_float(ed.y);
            float4 v = load4f(base + (size_t)ed.x * 256);
            acc.x = fmaf(w, v.x, acc.x);
            acc.y = fmaf(w, v.y, acc.y);
            acc.z = fmaf(w, v.z, acc.z);
            acc.w = fmaf(w, v.w, acc.w);
        }
        store4(&out[(size_t)wid * 256 + lane * 4], acc);
    } else {  // D == 128
        float2 acc = make_float2(0.f, 0.f);
        const bf16_t* base = feat + lane * 2;
        for (int e = beg; e < end; ++e) {
            int2 ed = edges[e];
            float w = __int_as_float(ed.y);
            float2 v = load2f(base + (size_t)ed.x * 128);
            acc.x = fmaf(w, v.x, acc.x);
            acc.y = fmaf(w, v.y, acc.y);
        }
        store2(&out[(size_t)wid * 128 + lane * 2], acc);
    }
}

// ---------------- MFMA GEMM: C(bf16,[M,256]) = A1@W1 (+A2@W2) (+bias) (+C) (relu?) ----
// A: bf16 row-major [M,K]; Wt: bf16 row-major [256,K] (pre-transposed weights).
// 128x128 tile / block of 256 threads; 4 waves in 2x2 grid of 64x64; BK=32.
template <bool TWOPASS>
__global__ __launch_bounds__(256) void gemm_mfma(
    const bf16_t* __restrict__ A1, const bf16_t* __restrict__ W1t,
    const bf16_t* __restrict__ A2, const bf16_t* __restrict__ W2t,
    const float* __restrict__ bias, bf16_t* __restrict__ C,
    int M, int K, int addc, int relu) {
    constexpr int LS = 40;  // 32 + 8 pad: breaks 8-way LDS bank aliasing
    __shared__ bf16_t As[128 * LS];
    __shared__ bf16_t Bs[128 * LS];
    const int t = threadIdx.x;
    const int lane = t & 63, wave = t >> 6;
    const int wm = (wave >> 1) * 64, wn = (wave & 1) * 64;
    const int rowBase = blockIdx.x * 128;
    const int colBase = blockIdx.y * 128;
    const int lm = lane & 15;    // row (A) / col (B) within 16-tile
    const int quad = lane >> 4;  // k-group 0..3
    f32x4 acc[4][4] = {};

    const int npass = TWOPASS ? 2 : 1;
    for (int pass = 0; pass < npass; ++pass) {
        const bf16_t* A = pass ? A2 : A1;
        const bf16_t* Wt = pass ? W2t : W1t;
        for (int k0 = 0; k0 < K; k0 += 32) {
#pragma unroll
            for (int i = 0; i < 2; ++i) {  // stage A tile: 128 rows x 32 k
                int li = t + i * 256;
                int r = li >> 2, c = (li & 3) * 8;
                int gm = rowBase + r;
                bf16x8 v = {};
                if (gm < M) v = *(const bf16x8*)&A[(size_t)gm * K + k0 + c];
                *(bf16x8*)&As[r * LS + c] = v;
            }
#pragma unroll
            for (int i = 0; i < 2; ++i) {  // stage B tile from Wt: 128 n-rows x 32 k
                int li = t + i * 256;
                int r = li >> 2, c = (li & 3) * 8;
                bf16x8 v = *(const bf16x8*)&Wt[(size_t)(colBase + r) * K + k0 + c];
                *(bf16x8*)&Bs[r * LS + c] = v;
            }
            __syncthreads();
            bf16x8 af[4], bfr[4];
#pragma unroll
            for (int i = 0; i < 4; ++i)
                af[i] = *(const bf16x8*)&As[(wm + i * 16 + lm) * LS + quad * 8];
#pragma unroll
            for (int j = 0; j < 4; ++j)
                bfr[j] = *(const bf16x8*)&Bs[(wn + j * 16 + lm) * LS + quad * 8];
#pragma unroll
            for (int i = 0; i < 4; ++i)
#pragma unroll
                for (int j = 0; j < 4; ++j)
                    acc[i][j] = __builtin_amdgcn_mfma_f32_16x16x32_bf16(af[i], bfr[j], acc[i][j], 0, 0, 0);
            __syncthreads();
        }
    }

    // epilogue: C row = rowBase+wm+i*16+quad*4+r, col = colBase+wn+j*16+lm
#pragma unroll
    for (int j = 0; j < 4; ++j) {
        int col = colBase + wn + j * 16 + lm;
        float bj = bias ? bias[col] : 0.f;
#pragma unroll
        for (int i = 0; i < 4; ++i) {
            int row0 = rowBase + wm + i * 16 + quad * 4;
#pragma unroll
            for (int r = 0; r < 4; ++r) {
                int row = row0 + r;
                if (row >= M) continue;
                float v = acc[i][j][r] + bj;
                bf16_t* cp = &C[(size_t)row * HD + col];
                if (addc) v += b2f(*cp);
                if (relu) v = fmaxf(v, 0.f);
                *cp = f2b(v);
            }
        }
    }
}

// ---------------- decoder ----------------
__global__ __launch_bounds__(256) void decode(
    const bf16_t* __restrict__ u3, const bf16_t* __restrict__ g3,
    const int* __restrict__ row, const int* __restrict__ col,
    float* __restrict__ out, int S) {
    int wid = (blockIdx.x * 256 + threadIdx.x) >> 6;
    int lane = threadIdx.x & 63;
    if (wid >= S) return;
    int r = row[wid], c = col[wid];
    float4 a = load4f(&u3[(size_t)r * 256 + lane * 4]);
    float4 b = load4f(&g3[(size_t)c * 256 + lane * 4]);
    float s = a.x * b.x + a.y * b.y + a.z * b.z + a.w * b.w;
#pragma unroll
    for (int d = 32; d > 0; d >>= 1) s += __shfl_down(s, d, 64);
    if (lane == 0) out[wid] = s;
}

extern "C" void kernel_launch(void* const* d_in, const int* in_sizes, int n_in,
                              void* d_out, int out_size, void* d_ws, size_t ws_size,
                              hipStream_t stream) {
    const float* x_user  = (const float*)d_in[0];
    const float* x_game  = (const float*)d_in[1];
    const float* emb_game= (const float*)d_in[2];
    const float* ew_ug   = (const float*)d_in[3];
    const float* ew_gu   = (const float*)d_in[4];
    const int* src_ug    = (const int*)d_in[5];
    const int* dst_ug    = (const int*)d_in[6];
    const int* src_gu    = (const int*)d_in[7];
    const int* dst_gu    = (const int*)d_in[8];
    const int* score_row = (const int*)d_in[9];
    const int* score_col = (const int*)d_in[10];
    const float* Wr_ug[3] = {(const float*)d_in[11], (const float*)d_in[17], (const float*)d_in[23]};
    const float* b_ug[3]  = {(const float*)d_in[12], (const float*)d_in[18], (const float*)d_in[24]};
    const float* Wo_g[3]  = {(const float*)d_in[13], (const float*)d_in[19], (const float*)d_in[25]};
    const float* Wr_gu[3] = {(const float*)d_in[14], (const float*)d_in[20], (const float*)d_in[26]};
    const float* b_gu[3]  = {(const float*)d_in[15], (const float*)d_in[21], (const float*)d_in[27]};
    const float* Wo_u[3]  = {(const float*)d_in[16], (const float*)d_in[22], (const float*)d_in[28]};
    float* out = (float*)d_out;
    (void)in_sizes; (void)n_in; (void)out_size;

    constexpr size_t WS_NEEDED = 183500000;
    if (ws_size < WS_NEEDED) return;  // clean fail, no OOB fault

    char* ws = (char*)d_ws;
    size_t off = 0;
    auto alloc = [&](size_t bytes) -> void* {
        void* p = ws + off;
        off += (bytes + 255) & ~(size_t)255;
        return p;
    };
    bf16_t* xg   = (bf16_t*)alloc((size_t)NG * 128 * 2);  //  5.12 MB
    bf16_t* xu   = (bf16_t*)alloc((size_t)NU * 128 * 2);  // 25.6 MB
    bf16_t* uA   = (bf16_t*)alloc((size_t)NU * HD * 2);   // 51.2 MB
    bf16_t* uB   = (bf16_t*)alloc((size_t)NU * HD * 2);   // 51.2 MB
    bf16_t* gA   = (bf16_t*)alloc((size_t)NG * HD * 2);   // 10.24 MB
    bf16_t* gB   = (bf16_t*)alloc((size_t)NG * HD * 2);   // 10.24 MB
    bf16_t* buf  = (bf16_t*)alloc((size_t)NG * HD * 2);   // 10.24 MB (Mbuf/Yg alias)
    int2*   e_ug = (int2*)  alloc((size_t)EE * 8);        //  8 MB
    int2*   e_gu = (int2*)  alloc((size_t)EE * 8);        //  8 MB
    // transposed bf16 weights
    bf16_t* WrugT[3], *WogT[3], *WrguT[3], *WouT[3];
    const int Ks[3] = {128, 256, 256};
    for (int l = 0; l < 3; ++l) {
        WrugT[l] = (bf16_t*)alloc((size_t)Ks[l] * HD * 2);
        WogT[l]  = (bf16_t*)alloc((size_t)Ks[l] * HD * 2);
        WrguT[l] = (bf16_t*)alloc((size_t)Ks[l] * HD * 2);
        WouT[l]  = (bf16_t*)alloc((size_t)Ks[l] * HD * 2);
    }
    int* rowptr_g = (int*)alloc((NG + 1) * 4);
    int* rowptr_u = (int*)alloc((NU + 1) * 4);
    int* cnt_g    = (int*)alloc(NG * 4);
    int* cnt_u    = (int*)alloc(NU * 4);
    int* bsum     = (int*)alloc(1024 * 4);

    auto build_csr = [&](const int* dst, const int* src, const float* ew, int n,
                         int* rowptr, int* cnt, int2* edges) {
        zero_i32<<<256, 256, 0, stream>>>(cnt, n);
        histo<<<1024, 256, 0, stream>>>(dst, cnt, EE);
        int nb = (n + 1023) / 1024;
        scan1<<<nb, 256, 0, stream>>>(cnt, rowptr, bsum, n);
        scan2<<<1, 64, 0, stream>>>(bsum, nb);
        scan3<<<nb, 256, 0, stream>>>(rowptr, bsum, n, EE);
        zero_i32<<<256, 256, 0, stream>>>(cnt, n);
        scatter_edges<<<1024, 256, 0, stream>>>(src, dst, ew, rowptr, cnt, edges, EE);
    };

    // preprocessing
    build_xg<<<(NG * 128 + 255) / 256, 256, 0, stream>>>(x_game, emb_game, xg);
    cvt_f2b<<<(NU * 128 / 4 + 255) / 256, 256, 0, stream>>>(x_user, xu, NU * 128 / 4);
    for (int l = 0; l < 3; ++l) {
        int nel = Ks[l] * HD, nb = (nel + 255) / 256;
        wt_bf16<<<nb, 256, 0, stream>>>(Wr_ug[l], WrugT[l], Ks[l]);
        wt_bf16<<<nb, 256, 0, stream>>>(Wo_g[l],  WogT[l],  Ks[l]);
        wt_bf16<<<nb, 256, 0, stream>>>(Wr_gu[l], WrguT[l], Ks[l]);
        wt_bf16<<<nb, 256, 0, stream>>>(Wo_u[l],  WouT[l],  Ks[l]);
    }
    build_csr(dst_ug, src_ug, ew_ug, NG, rowptr_g, cnt_g, e_ug);
    build_csr(dst_gu, src_gu, ew_gu, NU, rowptr_u, cnt_u, e_gu);

    const dim3 GG((NG + 127) / 128, 2), GU((NU + 127) / 128, 2);
    const int SEG_G = (NG + 3) / 4, SEG_U = (NU + 3) / 4;

    // ---- Layer 1 (K=128) ----
    seg_sum<128><<<SEG_G, 256, 0, stream>>>(xu, rowptr_g, e_ug, buf, NG);
    gemm_mfma<true><<<GG, 256, 0, stream>>>(buf, WrugT[0], xg, WogT[0], b_ug[0], gA, NG, 128, 0, 1);
    gemm_mfma<false><<<GG, 256, 0, stream>>>(xg, WrguT[0], nullptr, nullptr, nullptr, buf, NG, 128, 0, 0);
    seg_sum<256><<<SEG_U, 256, 0, stream>>>(buf, rowptr_u, e_gu, uA, NU);
    gemm_mfma<false><<<GU, 256, 0, stream>>>(xu, WouT[0], nullptr, nullptr, b_gu[0], uA, NU, 128, 1, 1);

    // ---- Layer 2 (K=256) ----
    seg_sum<256><<<SEG_G, 256, 0, stream>>>(uA, rowptr_g, e_ug, buf, NG);
    gemm_mfma<true><<<GG, 256, 0, stream>>>(buf, WrugT[1], gA, WogT[1], b_ug[1], gB, NG, 256, 0, 1);
    gemm_mfma<false><<<GG, 256, 0, stream>>>(gA, WrguT[1], nullptr, nullptr, nullptr, buf, NG, 256, 0, 0);
    seg_sum<256><<<SEG_U, 256, 0, stream>>>(buf, rowptr_u, e_gu, uB, NU);
    gemm_mfma<false><<<GU, 256, 0, stream>>>(uA, WouT[1], nullptr, nullptr, b_gu[1], uB, NU, 256, 1, 1);

    // ---- Layer 3 (K=256, no relu) ----
    seg_sum<256><<<SEG_G, 256, 0, stream>>>(uB, rowptr_g, e_ug, buf, NG);
    gemm_mfma<true><<<GG, 256, 0, stream>>>(buf, WrugT[2], gB, WogT[2], b_ug[2], gA, NG, 256, 0, 0);
    gemm_mfma<false><<<GG, 256, 0, stream>>>(gB, WrguT[2], nullptr, nullptr, nullptr, buf, NG, 256, 0, 0);
    seg_sum<256><<<SEG_U, 256, 0, stream>>>(buf, rowptr_u, e_gu, uA, NU);
    gemm_mfma<false><<<GU, 256, 0, stream>>>(uB, WouT[2], nullptr, nullptr, b_gu[2], uA, NU, 256, 1, 0);

    // ---- decode ----
    decode<<<(SS + 3) / 4, 256, 0, stream>>>(uA, gA, score_row, score_col, out, SS);
}

// Round 4
// 1169.568 us; speedup vs baseline: 1.9415x; 1.3237x over previous
//
#include <hip/hip_runtime.h>

typedef unsigned short bf16_t;  // raw bf16 bits
typedef __attribute__((ext_vector_type(8))) short bf16x8;
typedef __attribute__((ext_vector_type(4))) float f32x4;

static constexpr int NU = 100000;   // users
static constexpr int NG = 20000;    // games
static constexpr int HD = 256;      // hidden
static constexpr int EE = 1000000;  // edges per direction
static constexpr int SS = 500000;   // score pairs
static constexpr int NBG = 20;      // scan blocks for NG (1024 elems/block)
static constexpr int NBU = 98;      // scan blocks for NU

// ---------------- bf16 helpers ----------------
__device__ __forceinline__ float b2f(bf16_t u) {
    union { unsigned int i; float f; } x; x.i = ((unsigned int)u) << 16; return x.f;
}
__device__ __forceinline__ bf16_t f2b(float f) {
    union { float f; unsigned int i; } x; x.f = f;
    unsigned int r = x.i + 0x7FFF + ((x.i >> 16) & 1);  // RNE
    return (bf16_t)(r >> 16);
}

// accumulate 8 bf16 (packed in uint4) * w into acc[8]
__device__ __forceinline__ void accum8(float* acc, uint4 r, float w) {
    unsigned int u[4] = {r.x, r.y, r.z, r.w};
#pragma unroll
    for (int i = 0; i < 4; i++) {
        float lo = __uint_as_float(u[i] << 16);
        float hi = __uint_as_float(u[i] & 0xFFFF0000u);
        acc[2 * i]     = fmaf(w, lo, acc[2 * i]);
        acc[2 * i + 1] = fmaf(w, hi, acc[2 * i + 1]);
    }
}

// ---------------- preprocessing ----------------
// xg = bf16(concat(x_game, emb_game)); xu = bf16(x_user)  (float4 granular)
__global__ void prep_feats(const float* __restrict__ xgame, const float* __restrict__ emb,
                           const float* __restrict__ xuser,
                           bf16_t* __restrict__ xg, bf16_t* __restrict__ xu) {
    int id = blockIdx.x * 256 + threadIdx.x;
    const int ng4 = NG * 32;  // NG*128/4
    if (id < ng4) {
        int r = id >> 5, c = (id & 31) * 4;
        float4 v = (c < 64) ? *(const float4*)&xgame[(size_t)r * 64 + c]
                            : *(const float4*)&emb[(size_t)r * 64 + (c - 64)];
        ((ushort4*)xg)[id] = make_ushort4(f2b(v.x), f2b(v.y), f2b(v.z), f2b(v.w));
    } else {
        int j = id - ng4;
        if (j >= NU * 32) return;
        float4 v = ((const float4*)xuser)[j];
        ((ushort4*)xu)[j] = make_ushort4(f2b(v.x), f2b(v.y), f2b(v.z), f2b(v.w));
    }
}

// all 12 weights: K x 256 fp32 row-major -> 256 x K bf16 (transpose+convert)
struct WtArgs {
    const float* src[12];
    bf16_t* dst[12];
    int K[12];
    int off[13];
};
__global__ void wt_all(WtArgs a, int total) {
    int id = blockIdx.x * 256 + threadIdx.x;
    if (id >= total) return;
    int s = 0;
    while (id >= a.off[s + 1]) ++s;
    int local = id - a.off[s];
    int K = a.K[s];
    int k = local >> 8, n = local & 255;
    a.dst[s][(size_t)n * K + k] = f2b(a.src[s][local]);
}

// ---------------- CSR build (both edge types in one set of launches) ----------------
__global__ void zero_cnts(int* __restrict__ cg, int* __restrict__ cu) {
    for (int i = blockIdx.x * 256 + threadIdx.x; i < NG + NU; i += gridDim.x * 256) {
        if (i < NG) cg[i] = 0; else cu[i - NG] = 0;
    }
}

__global__ void histo2(const int* __restrict__ dug, const int* __restrict__ dgu,
                       int* __restrict__ cg, int* __restrict__ cu) {
    for (int i = blockIdx.x * blockDim.x + threadIdx.x; i < 2 * EE; i += gridDim.x * blockDim.x) {
        if (i < EE) atomicAdd(&cg[dug[i]], 1);
        else        atomicAdd(&cu[dgu[i - EE]], 1);
    }
}

__device__ __forceinline__ void scan1_body(const int* cnt, int* rowptr, int* bsum,
                                           int n, int lb) {
    __shared__ int sd[256];
    int t = threadIdx.x;
    int base = lb * 1024;
    int v[4]; int s = 0;
#pragma unroll
    for (int i = 0; i < 4; i++) {
        int idx = base + t * 4 + i;
        v[i] = (idx < n) ? cnt[idx] : 0;
        s += v[i];
    }
    sd[t] = s;
    __syncthreads();
    for (int off = 1; off < 256; off <<= 1) {
        int y = (t >= off) ? sd[t - off] : 0;
        __syncthreads();
        sd[t] += y;
        __syncthreads();
    }
    int run = sd[t] - s;
#pragma unroll
    for (int i = 0; i < 4; i++) {
        int idx = base + t * 4 + i;
        if (idx < n) rowptr[idx] = run;
        run += v[i];
    }
    if (t == 255) bsum[lb] = sd[255];
}

__global__ void scan1b(const int* __restrict__ cg, int* __restrict__ rpg, int* __restrict__ bsg,
                       const int* __restrict__ cu, int* __restrict__ rpu, int* __restrict__ bsu) {
    int b = blockIdx.x;
    if (b < NBG) scan1_body(cg, rpg, bsg, NG, b);
    else         scan1_body(cu, rpu, bsu, NU, b - NBG);
}

__global__ void scan2b(int* __restrict__ bsg, int* __restrict__ bsu) {
    if (blockIdx.x != 0) return;
    if (threadIdx.x == 0) {
        int run = 0;
        for (int i = 0; i < NBG; i++) { int v = bsg[i]; bsg[i] = run; run += v; }
    } else if (threadIdx.x == 1) {
        int run = 0;
        for (int i = 0; i < NBU; i++) { int v = bsu[i]; bsu[i] = run; run += v; }
    }
}

__device__ __forceinline__ void scan3_body(int* rowptr, const int* bsum, int n, int lb) {
    int t = threadIdx.x;
    int base = lb * 1024;
    int add = bsum[lb];
#pragma unroll
    for (int i = 0; i < 4; i++) {
        int idx = base + t * 4 + i;
        if (idx < n) rowptr[idx] += add;
    }
    if (lb == 0 && t == 0) rowptr[n] = EE;
}

__global__ void scan3b(int* __restrict__ rpg, const int* __restrict__ bsg,
                       int* __restrict__ rpu, const int* __restrict__ bsu) {
    int b = blockIdx.x;
    if (b < NBG) scan3_body(rpg, bsg, NG, b);
    else         scan3_body(rpu, bsu, NU, b - NBG);
}

__global__ void scatter2(const int* __restrict__ sug, const int* __restrict__ dug,
                         const float* __restrict__ wug,
                         const int* __restrict__ sgu, const int* __restrict__ dgu,
                         const float* __restrict__ wgu,
                         const int* __restrict__ rpg, const int* __restrict__ rpu,
                         int* __restrict__ cg, int* __restrict__ cu,
                         int2* __restrict__ eug, int2* __restrict__ egu) {
    for (int i = blockIdx.x * blockDim.x + threadIdx.x; i < 2 * EE; i += gridDim.x * blockDim.x) {
        if (i < EE) {
            int d = dug[i];
            int p = rpg[d] + atomicAdd(&cg[d], 1);
            eug[p] = make_int2(sug[i], __float_as_int(wug[i]));
        } else {
            int j = i - EE;
            int d = dgu[j];
            int p = rpu[d] + atomicAdd(&cu[d], 1);
            egu[p] = make_int2(sgu[j], __float_as_int(wgu[j]));
        }
    }
}

// ---------------- segment sum: wave split into D/8-lane subgroups, one edge each ----
// 16 B loads, 2x unroll => 4 independent edge-row loads in flight per wave.
template <int D>  // 128 or 256
__global__ __launch_bounds__(256) void seg_sum16(
    const bf16_t* __restrict__ feat, const int* __restrict__ rowptr,
    const int2* __restrict__ edges, bf16_t* __restrict__ out, int n_rows) {
    constexpr int LPE = D / 8;    // lanes per edge-row (16 B each)
    constexpr int EP = 64 / LPE;  // edges per batch
    int wid = (blockIdx.x * 256 + threadIdx.x) >> 6;
    int lane = threadIdx.x & 63;
    if (wid >= n_rows) return;
    int beg = rowptr[wid], end = rowptr[wid + 1];
    const int h = lane / LPE;   // which edge within batch
    const int cl = lane % LPE;  // 16B-column within row
    const uint4* fb = (const uint4*)feat;
    float acc[8] = {};
    for (int eb = beg; eb < end; eb += 2 * EP) {
        int e0 = eb + h, e1 = eb + EP + h;
        bool v0 = e0 < end, v1 = e1 < end;
        int2 ed0 = edges[v0 ? e0 : beg];
        int2 ed1 = edges[v1 ? e1 : beg];
        uint4 r0 = fb[(size_t)ed0.x * (D / 8) + cl];
        uint4 r1 = fb[(size_t)ed1.x * (D / 8) + cl];
        float w0 = v0 ? __int_as_float(ed0.y) : 0.f;
        float w1 = v1 ? __int_as_float(ed1.y) : 0.f;
        accum8(acc, r0, w0);
        accum8(acc, r1, w1);
    }
    // reduce across subgroups (lanes cl, cl+LPE, ...)
#pragma unroll
    for (int k = 0; k < 8; ++k) {
        acc[k] += __shfl_down(acc[k], 32, 64);
        if (LPE == 16) acc[k] += __shfl_down(acc[k], 16, 64);
    }
    if (lane < LPE) {
        uint4 o;
        o.x = (unsigned)f2b(acc[0]) | ((unsigned)f2b(acc[1]) << 16);
        o.y = (unsigned)f2b(acc[2]) | ((unsigned)f2b(acc[3]) << 16);
        o.z = (unsigned)f2b(acc[4]) | ((unsigned)f2b(acc[5]) << 16);
        o.w = (unsigned)f2b(acc[6]) | ((unsigned)f2b(acc[7]) << 16);
        ((uint4*)(out + (size_t)wid * D))[lane] = o;
    }
}

// ---------------- MFMA GEMM: C(bf16,[M,256]) = A1@W1 (+A2@W2) (+bias) (+C) (relu?) ----
template <bool TWOPASS>
__global__ __launch_bounds__(256) void gemm_mfma(
    const bf16_t* __restrict__ A1, const bf16_t* __restrict__ W1t,
    const bf16_t* __restrict__ A2, const bf16_t* __restrict__ W2t,
    const float* __restrict__ bias, bf16_t* __restrict__ C,
    int M, int K, int addc, int relu) {
    constexpr int LS = 40;
    __shared__ bf16_t As[128 * LS];
    __shared__ bf16_t Bs[128 * LS];
    const int t = threadIdx.x;
    const int lane = t & 63, wave = t >> 6;
    const int wm = (wave >> 1) * 64, wn = (wave & 1) * 64;
    const int rowBase = blockIdx.x * 128;
    const int colBase = blockIdx.y * 128;
    const int lm = lane & 15;
    const int quad = lane >> 4;
    f32x4 acc[4][4] = {};

    const int npass = TWOPASS ? 2 : 1;
    for (int pass = 0; pass < npass; ++pass) {
        const bf16_t* A = pass ? A2 : A1;
        const bf16_t* Wt = pass ? W2t : W1t;
        for (int k0 = 0; k0 < K; k0 += 32) {
#pragma unroll
            for (int i = 0; i < 2; ++i) {
                int li = t + i * 256;
                int r = li >> 2, c = (li & 3) * 8;
                int gm = rowBase + r;
                bf16x8 v = {};
                if (gm < M) v = *(const bf16x8*)&A[(size_t)gm * K + k0 + c];
                *(bf16x8*)&As[r * LS + c] = v;
            }
#pragma unroll
            for (int i = 0; i < 2; ++i) {
                int li = t + i * 256;
                int r = li >> 2, c = (li & 3) * 8;
                bf16x8 v = *(const bf16x8*)&Wt[(size_t)(colBase + r) * K + k0 + c];
                *(bf16x8*)&Bs[r * LS + c] = v;
            }
            __syncthreads();
            bf16x8 af[4], bfr[4];
#pragma unroll
            for (int i = 0; i < 4; ++i)
                af[i] = *(const bf16x8*)&As[(wm + i * 16 + lm) * LS + quad * 8];
#pragma unroll
            for (int j = 0; j < 4; ++j)
                bfr[j] = *(const bf16x8*)&Bs[(wn + j * 16 + lm) * LS + quad * 8];
#pragma unroll
            for (int i = 0; i < 4; ++i)
#pragma unroll
                for (int j = 0; j < 4; ++j)
                    acc[i][j] = __builtin_amdgcn_mfma_f32_16x16x32_bf16(af[i], bfr[j], acc[i][j], 0, 0, 0);
            __syncthreads();
        }
    }

#pragma unroll
    for (int j = 0; j < 4; ++j) {
        int col = colBase + wn + j * 16 + lm;
        float bj = bias ? bias[col] : 0.f;
#pragma unroll
        for (int i = 0; i < 4; ++i) {
            int row0 = rowBase + wm + i * 16 + quad * 4;
#pragma unroll
            for (int r = 0; r < 4; ++r) {
                int row = row0 + r;
                if (row >= M) continue;
                float v = acc[i][j][r] + bj;
                bf16_t* cp = &C[(size_t)row * HD + col];
                if (addc) v += b2f(*cp);
                if (relu) v = fmaxf(v, 0.f);
                *cp = f2b(v);
            }
        }
    }
}

// ---------------- decoder: 2 pairs per wave, 16 B loads ----------------
__global__ __launch_bounds__(256) void decode2(
    const bf16_t* __restrict__ u3, const bf16_t* __restrict__ g3,
    const int* __restrict__ row, const int* __restrict__ col,
    float* __restrict__ out, int S) {
    int wid = (blockIdx.x * 256 + threadIdx.x) >> 6;
    int lane = threadIdx.x & 63;
    int p = wid * 2 + (lane >> 5);
    int cl = lane & 31;
    if (p >= S) p = S - 1;  // tail lanes recompute last pair (benign dup store)
    int r = row[p], c = col[p];
    uint4 a = ((const uint4*)(u3 + (size_t)r * 256))[cl];
    uint4 b = ((const uint4*)(g3 + (size_t)c * 256))[cl];
    float s = 0.f;
    unsigned ua[4] = {a.x, a.y, a.z, a.w}, ub[4] = {b.x, b.y, b.z, b.w};
#pragma unroll
    for (int i = 0; i < 4; i++) {
        float alo = __uint_as_float(ua[i] << 16), ahi = __uint_as_float(ua[i] & 0xFFFF0000u);
        float blo = __uint_as_float(ub[i] << 16), bhi = __uint_as_float(ub[i] & 0xFFFF0000u);
        s = fmaf(alo, blo, s);
        s = fmaf(ahi, bhi, s);
    }
#pragma unroll
    for (int d = 16; d > 0; d >>= 1) s += __shfl_down(s, d, 64);
    if (cl == 0) out[p] = s;
}

extern "C" void kernel_launch(void* const* d_in, const int* in_sizes, int n_in,
                              void* d_out, int out_size, void* d_ws, size_t ws_size,
                              hipStream_t stream) {
    const float* x_user  = (const float*)d_in[0];
    const float* x_game  = (const float*)d_in[1];
    const float* emb_game= (const float*)d_in[2];
    const float* ew_ug   = (const float*)d_in[3];
    const float* ew_gu   = (const float*)d_in[4];
    const int* src_ug    = (const int*)d_in[5];
    const int* dst_ug    = (const int*)d_in[6];
    const int* src_gu    = (const int*)d_in[7];
    const int* dst_gu    = (const int*)d_in[8];
    const int* score_row = (const int*)d_in[9];
    const int* score_col = (const int*)d_in[10];
    const float* Wr_ug[3] = {(const float*)d_in[11], (const float*)d_in[17], (const float*)d_in[23]};
    const float* b_ug[3]  = {(const float*)d_in[12], (const float*)d_in[18], (const float*)d_in[24]};
    const float* Wo_g[3]  = {(const float*)d_in[13], (const float*)d_in[19], (const float*)d_in[25]};
    const float* Wr_gu[3] = {(const float*)d_in[14], (const float*)d_in[20], (const float*)d_in[26]};
    const float* b_gu[3]  = {(const float*)d_in[15], (const float*)d_in[21], (const float*)d_in[27]};
    const float* Wo_u[3]  = {(const float*)d_in[16], (const float*)d_in[22], (const float*)d_in[28]};
    float* out = (float*)d_out;
    (void)in_sizes; (void)n_in; (void)out_size;

    constexpr size_t WS_NEEDED = 183500000;
    if (ws_size < WS_NEEDED) return;  // clean fail, no OOB fault

    char* ws = (char*)d_ws;
    size_t off = 0;
    auto alloc = [&](size_t bytes) -> void* {
        void* p = ws + off;
        off += (bytes + 255) & ~(size_t)255;
        return p;
    };
    bf16_t* xg   = (bf16_t*)alloc((size_t)NG * 128 * 2);
    bf16_t* xu   = (bf16_t*)alloc((size_t)NU * 128 * 2);
    bf16_t* uA   = (bf16_t*)alloc((size_t)NU * HD * 2);
    bf16_t* uB   = (bf16_t*)alloc((size_t)NU * HD * 2);
    bf16_t* gA   = (bf16_t*)alloc((size_t)NG * HD * 2);
    bf16_t* gB   = (bf16_t*)alloc((size_t)NG * HD * 2);
    bf16_t* buf  = (bf16_t*)alloc((size_t)NG * HD * 2);
    int2*   e_ug = (int2*)  alloc((size_t)EE * 8);
    int2*   e_gu = (int2*)  alloc((size_t)EE * 8);
    bf16_t* WrugT[3], *WogT[3], *WrguT[3], *WouT[3];
    const int Ks[3] = {128, 256, 256};
    for (int l = 0; l < 3; ++l) {
        WrugT[l] = (bf16_t*)alloc((size_t)Ks[l] * HD * 2);
        WogT[l]  = (bf16_t*)alloc((size_t)Ks[l] * HD * 2);
        WrguT[l] = (bf16_t*)alloc((size_t)Ks[l] * HD * 2);
        WouT[l]  = (bf16_t*)alloc((size_t)Ks[l] * HD * 2);
    }
    int* rowptr_g = (int*)alloc((NG + 1) * 4);
    int* rowptr_u = (int*)alloc((NU + 1) * 4);
    int* cnt_g    = (int*)alloc(NG * 4);
    int* cnt_u    = (int*)alloc(NU * 4);
    int* bsum_g   = (int*)alloc(512 * 4);
    int* bsum_u   = (int*)alloc(512 * 4);

    // ---- preprocessing ----
    {
        int n4 = NG * 32 + NU * 32;
        prep_feats<<<(n4 + 255) / 256, 256, 0, stream>>>(x_game, emb_game, x_user, xg, xu);
        WtArgs wa;
        const float* srcs[12] = {Wr_ug[0], Wo_g[0], Wr_gu[0], Wo_u[0],
                                 Wr_ug[1], Wo_g[1], Wr_gu[1], Wo_u[1],
                                 Wr_ug[2], Wo_g[2], Wr_gu[2], Wo_u[2]};
        bf16_t* dsts[12] = {WrugT[0], WogT[0], WrguT[0], WouT[0],
                            WrugT[1], WogT[1], WrguT[1], WouT[1],
                            WrugT[2], WogT[2], WrguT[2], WouT[2]};
        int total = 0;
        for (int i = 0; i < 12; ++i) {
            wa.src[i] = srcs[i]; wa.dst[i] = dsts[i];
            wa.K[i] = Ks[i / 4]; wa.off[i] = total;
            total += Ks[i / 4] * HD;
        }
        wa.off[12] = total;
        wt_all<<<(total + 255) / 256, 256, 0, stream>>>(wa, total);
    }
    // ---- CSR build (both directions) ----
    zero_cnts<<<256, 256, 0, stream>>>(cnt_g, cnt_u);
    histo2<<<2048, 256, 0, stream>>>(dst_ug, dst_gu, cnt_g, cnt_u);
    scan1b<<<NBG + NBU, 256, 0, stream>>>(cnt_g, rowptr_g, bsum_g, cnt_u, rowptr_u, bsum_u);
    scan2b<<<1, 64, 0, stream>>>(bsum_g, bsum_u);
    scan3b<<<NBG + NBU, 256, 0, stream>>>(rowptr_g, bsum_g, rowptr_u, bsum_u);
    zero_cnts<<<256, 256, 0, stream>>>(cnt_g, cnt_u);
    scatter2<<<2048, 256, 0, stream>>>(src_ug, dst_ug, ew_ug, src_gu, dst_gu, ew_gu,
                                       rowptr_g, rowptr_u, cnt_g, cnt_u, e_ug, e_gu);

    const dim3 GG((NG + 127) / 128, 2), GU((NU + 127) / 128, 2);
    const int SEG_G = (NG + 3) / 4, SEG_U = (NU + 3) / 4;

    // ---- Layer 1 (K=128) ----
    seg_sum16<128><<<SEG_G, 256, 0, stream>>>(xu, rowptr_g, e_ug, buf, NG);
    gemm_mfma<true><<<GG, 256, 0, stream>>>(buf, WrugT[0], xg, WogT[0], b_ug[0], gA, NG, 128, 0, 1);
    gemm_mfma<false><<<GG, 256, 0, stream>>>(xg, WrguT[0], nullptr, nullptr, nullptr, buf, NG, 128, 0, 0);
    seg_sum16<256><<<SEG_U, 256, 0, stream>>>(buf, rowptr_u, e_gu, uA, NU);
    gemm_mfma<false><<<GU, 256, 0, stream>>>(xu, WouT[0], nullptr, nullptr, b_gu[0], uA, NU, 128, 1, 1);

    // ---- Layer 2 (K=256) ----
    seg_sum16<256><<<SEG_G, 256, 0, stream>>>(uA, rowptr_g, e_ug, buf, NG);
    gemm_mfma<true><<<GG, 256, 0, stream>>>(buf, WrugT[1], gA, WogT[1], b_ug[1], gB, NG, 256, 0, 1);
    gemm_mfma<false><<<GG, 256, 0, stream>>>(gA, WrguT[1], nullptr, nullptr, nullptr, buf, NG, 256, 0, 0);
    seg_sum16<256><<<SEG_U, 256, 0, stream>>>(buf, rowptr_u, e_gu, uB, NU);
    gemm_mfma<false><<<GU, 256, 0, stream>>>(uA, WouT[1], nullptr, nullptr, b_gu[1], uB, NU, 256, 1, 1);

    // ---- Layer 3 (K=256, no relu) ----
    seg_sum16<256><<<SEG_G, 256, 0, stream>>>(uB, rowptr_g, e_ug, buf, NG);
    gemm_mfma<true><<<GG, 256, 0, stream>>>(buf, WrugT[2], gB, WogT[2], b_ug[2], gA, NG, 256, 0, 0);
    gemm_mfma<false><<<GG, 256, 0, stream>>>(gB, WrguT[2], nullptr, nullptr, nullptr, buf, NG, 256, 0, 0);
    seg_sum16<256><<<SEG_U, 256, 0, stream>>>(buf, rowptr_u, e_gu, uA, NU);
    gemm_mfma<false><<<GU, 256, 0, stream>>>(uB, WouT[2], nullptr, nullptr, b_gu[2], uA, NU, 256, 1, 0);

    // ---- decode ----
    decode2<<<((SS + 1) / 2 + 3) / 4, 256, 0, stream>>>(uA, gA, score_row, score_col, out, SS);
}